// Round 10
// baseline (319.552 us; speedup 1.0000x reference)
//
#include <hip/hip_runtime.h>
#include <math.h>

typedef unsigned long long ull;

#define N      512
#define DIN    256
#define LAM    0.43f
#define MAGIC  0x4D535431u

// ---------------------------------------------------------------------------
// ws word offsets (floats). Flags one-shot, compared ==MAGIC (0xAA/0 safe).
//   [4] ldready [5] t0ready [6] t0bits
//   [8..71] blkmax   [128..639] ae_part   +1024 lat[1024]
//   +2048 xd[262144]   +264192 ld[262144]
//   +526336 toplist u64[2][512][16] (=32768 floats; fully rewritten pre-use)
//   +559104 bar u32[2][64]
// end ~559360 floats ~2.24 MB
// ---------------------------------------------------------------------------
#define OFF_LDREADY 4
#define OFF_T0READY 5
#define OFF_T0BITS  6
#define OFF_BLKMAX  8
#define OFF_AEPART  128
#define OFF_LAT     1024
#define OFF_XD      2048
#define OFF_LD      (2048 + 262144)
#define OFF_TOP     526336
#define OFF_BAR     (OFF_TOP + 32768)

__device__ __forceinline__ unsigned ld_acq(unsigned* p) {
    return __hip_atomic_load(p, __ATOMIC_ACQUIRE, __HIP_MEMORY_SCOPE_AGENT);
}
__device__ __forceinline__ void st_rel(unsigned* p, unsigned v) {
    __hip_atomic_store(p, v, __ATOMIC_RELEASE, __HIP_MEMORY_SCOPE_AGENT);
}
__device__ __forceinline__ unsigned ld_rlx(unsigned* p) {
    return __hip_atomic_load(p, __ATOMIC_RELAXED, __HIP_MEMORY_SCOPE_AGENT);
}
__device__ __forceinline__ void spin_magic(unsigned* p) {
    while (ld_acq(p) != MAGIC) __builtin_amdgcn_s_sleep(1);
}

// ============ kernel 1: fused MLP (blocks 0..511) + pdist_x (512..575) ======
// (unchanged from round 7 — proven)
__global__ __launch_bounds__(256) void fused_mlp_pdistx_kernel(
    const float* __restrict__ x,
    const float* __restrict__ W1, const float* __restrict__ b1,
    const float* __restrict__ W2, const float* __restrict__ b2,
    const float* __restrict__ Wm, const float* __restrict__ bm,
    const float* __restrict__ W3, const float* __restrict__ b3,
    const float* __restrict__ W4, const float* __restrict__ b4,
    const float* __restrict__ W5, const float* __restrict__ b5,
    float* __restrict__ lat_out, float* __restrict__ ae_part,
    float* __restrict__ xd, float* __restrict__ blkmax)
{
    const int tid = threadIdx.x;

    if (blockIdx.x < 512) {
        __shared__ float xs[256];
        __shared__ float h1[128];
        __shared__ float h2[64];
        __shared__ float latv[2];
        __shared__ float h3[64];
        __shared__ float h4[128];
        __shared__ float red[4];

        const int row = blockIdx.x;
        xs[tid] = x[(size_t)row * DIN + tid];
        __syncthreads();

        if (tid < 128) {
            float s = b1[tid];
            for (int k = 0; k < 256; ++k) s = fmaf(xs[k], W1[k * 128 + tid], s);
            h1[tid] = fmaxf(s, 0.f);
        }
        __syncthreads();

        if (tid < 64) {
            float s = b2[tid];
            for (int k = 0; k < 128; ++k) s = fmaf(h1[k], W2[k * 64 + tid], s);
            h2[tid] = fmaxf(s, 0.f);
        }
        __syncthreads();

        if (tid < 2) {
            float s = bm[tid];
            for (int k = 0; k < 64; ++k) s = fmaf(h2[k], Wm[k * 2 + tid], s);
            latv[tid] = s;
            lat_out[(size_t)row * 2 + tid] = s;
        }
        __syncthreads();

        if (tid < 64) {
            float s = b3[tid];
            s = fmaf(latv[0], W3[tid], s);
            s = fmaf(latv[1], W3[64 + tid], s);
            h3[tid] = fmaxf(s, 0.f);
        }
        __syncthreads();

        if (tid < 128) {
            float s = b4[tid];
            for (int k = 0; k < 64; ++k) s = fmaf(h3[k], W4[k * 128 + tid], s);
            h4[tid] = fmaxf(s, 0.f);
        }
        __syncthreads();

        float s = b5[tid];
        for (int k = 0; k < 128; ++k) s = fmaf(h4[k], W5[k * 256 + tid], s);
        float diff = xs[tid] - s;
        float a = diff * diff;

        #pragma unroll
        for (int m = 1; m < 64; m <<= 1) a += __shfl_xor(a, m, 64);
        if ((tid & 63) == 0) red[tid >> 6] = a;
        __syncthreads();
        if (tid == 0) ae_part[row] = red[0] + red[1] + red[2] + red[3];
    } else {
        __shared__ float As[32][65];
        __shared__ float Bs[32][65];
        __shared__ float red2[4];

        const int bid = blockIdx.x - 512;
        const int bi = bid & 7, bj = bid >> 3;
        const int i0 = bi * 64, j0 = bj * 64;
        const int ty = tid >> 4, tx = tid & 15;

        float acc[4][4];
        #pragma unroll
        for (int i = 0; i < 4; ++i)
            #pragma unroll
            for (int j = 0; j < 4; ++j) acc[i][j] = 0.f;

        for (int kk = 0; kk < DIN; kk += 32) {
            #pragma unroll
            for (int s = tid; s < 512; s += 256) {
                int r = s >> 3, c4 = (s & 7) << 2;
                float4 va = *(const float4*)(x + (size_t)(i0 + r) * DIN + kk + c4);
                As[c4 + 0][r] = va.x; As[c4 + 1][r] = va.y;
                As[c4 + 2][r] = va.z; As[c4 + 3][r] = va.w;
                float4 vb = *(const float4*)(x + (size_t)(j0 + r) * DIN + kk + c4);
                Bs[c4 + 0][r] = vb.x; Bs[c4 + 1][r] = vb.y;
                Bs[c4 + 2][r] = vb.z; Bs[c4 + 3][r] = vb.w;
            }
            __syncthreads();
            #pragma unroll 8
            for (int k = 0; k < 32; ++k) {
                float a[4], b[4];
                #pragma unroll
                for (int i = 0; i < 4; ++i) a[i] = As[k][ty + 16 * i];
                #pragma unroll
                for (int j = 0; j < 4; ++j) b[j] = Bs[k][tx + 16 * j];
                #pragma unroll
                for (int i = 0; i < 4; ++i)
                    #pragma unroll
                    for (int j = 0; j < 4; ++j) {
                        float d = a[i] - b[j];
                        acc[i][j] = fmaf(d, d, acc[i][j]);
                    }
            }
            __syncthreads();
        }

        float lmax = 0.f;
        #pragma unroll
        for (int i = 0; i < 4; ++i)
            #pragma unroll
            for (int j = 0; j < 4; ++j) {
                float dd = sqrtf(acc[i][j]);
                int r = i0 + ty + 16 * i, c = j0 + tx + 16 * j;
                xd[(size_t)r * N + c] = dd;
                lmax = fmaxf(lmax, dd);
            }

        #pragma unroll
        for (int m = 32; m >= 1; m >>= 1) lmax = fmaxf(lmax, __shfl_xor(lmax, m, 64));
        if ((tid & 63) == 0) red2[tid >> 6] = lmax;
        __syncthreads();
        if (tid == 0)
            blkmax[bid] = fmaxf(fmaxf(red2[0], red2[1]), fmaxf(red2[2], red2[3]));
    }
}

// ============ kernel 2: top-16-list Boruvka MST x2 ==========================
// 128 blocks x 256. Blocks 0..63 -> MST(xd), 64..127 -> MST(ld).
// Workers: (m=1: compute own 8 ld rows) + build exact sorted top-16 outgoing
// candidate lists per row (16 wave-argmin extractions) -> ONE global barrier.
// Finisher (wb==0): loads all lists into LDS (64 KB) and runs EVERY Boruvka
// phase block-locally: monotone cursor walk (same-comp skips are permanent),
// read-check+atomicMin candidate select, rare full-row fallback when a row's
// 16 entries are all same-comp (exact correctness), hook + pointer doubling.
// Key = w<<18 | r<<9 | j  (unique weights -> unique MST = Kruskal's set).
__global__ __launch_bounds__(256) void mst_topk_kernel(
    const float* __restrict__ xd, float* __restrict__ ld,
    const float* __restrict__ lat, const float* __restrict__ latent_norm,
    const float* __restrict__ blkmax, const float* __restrict__ ae_part,
    float* __restrict__ wsf, float* __restrict__ out)
{
    __shared__ ull tl[8192];              // [512][16] candidate lists
    __shared__ unsigned comp_a[512];
    __shared__ ull cand[512];
    __shared__ int tgt[512];
    __shared__ int cur[512];
    __shared__ int fbq[512];
    __shared__ unsigned short eu[512], ev[512];
    __shared__ float ew[512];
    __shared__ float latx[512], laty[512];
    __shared__ float s_red[4];
    __shared__ float s_xdm;
    __shared__ int s_ecnt, s_nq;

    const int tid = threadIdx.x;
    const int blk = blockIdx.x;
    const int m   = blk >> 6;
    const int wb  = blk & 63;
    const int wave = tid >> 6, lane = tid & 63;
    const int r0 = wb << 3;

    unsigned* ldready = (unsigned*)(wsf + OFF_LDREADY);
    unsigned* t0ready = (unsigned*)(wsf + OFF_T0READY);
    unsigned* t0bits  = (unsigned*)(wsf + OFF_T0BITS);
    ull* top = (ull*)(wsf + OFF_TOP) + (size_t)m * 8192;
    unsigned* bar = (unsigned*)(wsf + OFF_BAR) + (size_t)m * 64;

    const float* Dm = m ? ld : xd;
    const float* Om = m ? xd : ld;

    // ---- m=1: compute own 8 ld rows (lat from kernel 1) ----
    if (m == 1) {
        for (int i = tid; i < 512; i += 256) {
            float2 v = *(const float2*)(lat + 2 * i);
            latx[i] = v.x; laty[i] = v.y;
        }
        __syncthreads();
        for (int q = tid; q < 1024; q += 256) {   // 8 rows x 128 float4
            int rr = r0 + (q >> 7);
            int j  = (q & 127) << 2;
            float xi = latx[rr], yi = laty[rr];
            float dx0 = xi - latx[j + 0], dy0 = yi - laty[j + 0];
            float dx1 = xi - latx[j + 1], dy1 = yi - laty[j + 1];
            float dx2 = xi - latx[j + 2], dy2 = yi - laty[j + 2];
            float dx3 = xi - latx[j + 3], dy3 = yi - laty[j + 3];
            float4 o;
            o.x = sqrtf(fmaf(dx0, dx0, dy0 * dy0));
            o.y = sqrtf(fmaf(dx1, dx1, dy1 * dy1));
            o.z = sqrtf(fmaf(dx2, dx2, dy2 * dy2));
            o.w = sqrtf(fmaf(dx3, dx3, dy3 * dy3));
            *(float4*)(ld + (size_t)rr * N + j) = o;
        }
        __syncthreads();
    }

    // ---- build top-16 lists: wave handles rows r0+2*wave, r0+2*wave+1 ----
    #pragma unroll
    for (int rr = 0; rr < 2; ++rr) {
        const int r = r0 + (wave << 1) + rr;
        const float4* rp = (const float4*)(Dm + (size_t)r * N + (lane << 3));
        float4 fa = rp[0], fb = rp[1];
        float wv[8] = {fa.x, fa.y, fa.z, fa.w, fb.x, fb.y, fb.z, fb.w};
        ull k[8];
        #pragma unroll
        for (int s = 0; s < 8; ++s) {
            int j = (lane << 3) + s;
            k[s] = (j == r) ? ~0ULL
                 : (((ull)__float_as_uint(wv[s]) << 18) | ((ull)r << 9) | (unsigned)j);
        }
        for (int e = 0; e < 16; ++e) {
            ull bk = k[0];
            #pragma unroll
            for (int s = 1; s < 8; ++s) bk = (k[s] < bk) ? k[s] : bk;
            #pragma unroll
            for (int mm = 1; mm <= 32; mm <<= 1) {
                ull o = __shfl_xor(bk, mm, 64);
                if (o < bk) bk = o;
            }
            #pragma unroll
            for (int s = 0; s < 8; ++s) if (k[s] == bk) k[s] = ~0ULL;
            if (lane == 0) top[(size_t)r * 16 + e] = bk;
        }
    }
    __syncthreads();                       // drains global stores (vmcnt)
    if (tid == 0) st_rel(&bar[wb], MAGIC);
    if (wb != 0) return;                   // workers done

    // =================== finisher (block 0 / 64) ===================
    if (tid < 64) spin_magic(&bar[tid]);
    __syncthreads();
    if (m == 1 && tid == 0) st_rel(ldready, MAGIC);  // full ld now visible

    // load lists (coalesced, post-acquire)
    for (int i = tid; i < 8192; i += 256) tl[i] = top[i];
    for (int i = tid; i < 512; i += 256) { comp_a[i] = (unsigned)i; cur[i] = 0; }
    if (tid == 0) s_ecnt = 0;
    __syncthreads();

    int nc = 512;
    for (int ph = 0; ph < 9 && nc > 1; ++ph) {
        for (int i = tid; i < 512; i += 256) cand[i] = ~0ULL;
        if (tid == 0) s_nq = 0;
        __syncthreads();

        // --- walk: 2 rows/thread, monotone cursor over sorted list ---
        #pragma unroll
        for (int rr = 0; rr < 2; ++rr) {
            int r = tid + (rr << 8);
            unsigned c = comp_a[r];
            int e = cur[r];
            ull found = ~0ULL;
            while (e < 16) {
                ull kk = tl[r * 16 + e];
                if (comp_a[kk & 511] != c) { found = kk; break; }
                ++e;
            }
            cur[r] = e;
            if (e == 16) { int q = atomicAdd(&s_nq, 1); fbq[q] = r; }
            else if (found < cand[c]) atomicMin(&cand[c], found);
        }
        __syncthreads();

        // --- fallbacks: one wave per exhausted row, full-row rescan ---
        for (int q = wave; q < s_nq; q += 4) {
            int r = fbq[q];
            unsigned c = comp_a[r];
            const float4* rp = (const float4*)(Dm + (size_t)r * N + (lane << 3));
            float4 fa = rp[0], fb = rp[1];
            float wv[8] = {fa.x, fa.y, fa.z, fa.w, fb.x, fb.y, fb.z, fb.w};
            ull bk = ~0ULL;
            #pragma unroll
            for (int s = 0; s < 8; ++s) {
                int j = (lane << 3) + s;
                if (j != r && comp_a[j] != c) {
                    ull kk = ((ull)__float_as_uint(wv[s]) << 18)
                           | ((ull)r << 9) | (unsigned)j;
                    if (kk < bk) bk = kk;
                }
            }
            #pragma unroll
            for (int mm = 1; mm <= 32; mm <<= 1) {
                ull o = __shfl_xor(bk, mm, 64);
                if (o < bk) bk = o;
            }
            if (lane == 0 && bk != ~0ULL && bk < cand[c]) atomicMin(&cand[c], bk);
        }
        __syncthreads();

        // --- hook (mutual pairs broken by index) + record edges ---
        for (int i = tid; i < 512; i += 256) {
            int t = -1;
            if (comp_a[i] == (unsigned)i && cand[i] != ~0ULL)
                t = (int)comp_a[cand[i] & 511];
            tgt[i] = t;
        }
        __syncthreads();
        for (int i = tid; i < 512; i += 256) {
            int s = tgt[i];
            if (s >= 0 && !(tgt[s] == i && i > s)) {
                comp_a[i] = (unsigned)s;
                int e2 = atomicAdd(&s_ecnt, 1);
                ull cc = cand[i];
                eu[e2] = (unsigned short)((cc >> 9) & 511);
                ev[e2] = (unsigned short)(cc & 511);
                ew[e2] = __uint_as_float((unsigned)(cc >> 18));
            }
        }
        __syncthreads();
        for (int dd = 0; dd < 9; ++dd) {   // pointer doubling to roots
            unsigned a = comp_a[comp_a[tid]];
            unsigned b = comp_a[comp_a[tid + 256]];
            __syncthreads();
            comp_a[tid] = a; comp_a[tid + 256] = b;
            __syncthreads();
        }
        nc = 512 - s_ecnt;
        __syncthreads();
    }

    // =================== epilogue ===================
    if (tid < 64) {
        float mx = blkmax[tid];
        #pragma unroll
        for (int mm = 32; mm >= 1; mm >>= 1) mx = fmaxf(mx, __shfl_xor(mx, mm, 64));
        if (tid == 0) s_xdm = mx;
    }
    __syncthreads();
    const float xdm = s_xdm;
    const float lnv = latent_norm[0];
    const float sD = (m == 0) ? 1.f / xdm : 1.f / lnv;
    const float sO = (m == 0) ? 1.f / lnv : 1.f / xdm;

    if (m == 0) {                          // need full ld for Om reads
        if (tid == 0) spin_magic(ldready);
        __syncthreads();
    }

    const int ne = s_ecnt;                 // 511
    float acc = 0.f;
    for (int i = tid; i < ne; i += 256) {
        float de = ew[i];
        float oe = Om[(size_t)eu[i] * N + ev[i]];
        float c = sD * de - sO * oe;
        acc = fmaf(c, c, acc);
    }
    #pragma unroll
    for (int mm = 32; mm >= 1; mm >>= 1) acc += __shfl_xor(acc, mm, 64);
    if ((tid & 63) == 0) s_red[tid >> 6] = acc;
    __syncthreads();

    if (m == 0) {
        if (tid == 0) {
            float t0 = s_red[0] + s_red[1] + s_red[2] + s_red[3];
            __hip_atomic_store(t0bits, __float_as_uint(t0), __ATOMIC_RELAXED,
                               __HIP_MEMORY_SCOPE_AGENT);
            st_rel(t0ready, MAGIC);
        }
    } else {
        float t1 = 0.f;
        if (tid == 0) t1 = s_red[0] + s_red[1] + s_red[2] + s_red[3];
        __syncthreads();                   // s_red reused
        float a = ae_part[tid] + ae_part[tid + 256];
        #pragma unroll
        for (int mm = 32; mm >= 1; mm >>= 1) a += __shfl_xor(a, mm, 64);
        if ((tid & 63) == 0) s_red[tid >> 6] = a;
        __syncthreads();
        if (tid == 0) {
            float ae = s_red[0] + s_red[1] + s_red[2] + s_red[3];
            spin_magic(t0ready);
            float t0 = __uint_as_float(ld_rlx(t0bits));
            out[0] = ae * (1.f / (float)(N * DIN))
                   + (LAM * (t0 + t1)) * (1.f / (float)N);
        }
    }
}

extern "C" void kernel_launch(void* const* d_in, const int* in_sizes, int n_in,
                              void* d_out, int out_size, void* d_ws, size_t ws_size,
                              hipStream_t stream) {
    (void)in_sizes; (void)n_in; (void)out_size; (void)ws_size;
    const float* x   = (const float*)d_in[0];
    // d_in[1] = label (unused)
    const float* W1  = (const float*)d_in[2];
    const float* b1  = (const float*)d_in[3];
    const float* W2  = (const float*)d_in[4];
    const float* b2  = (const float*)d_in[5];
    const float* Wm  = (const float*)d_in[6];
    const float* bm  = (const float*)d_in[7];
    const float* W3  = (const float*)d_in[8];
    const float* b3  = (const float*)d_in[9];
    const float* W4  = (const float*)d_in[10];
    const float* b4  = (const float*)d_in[11];
    const float* W5  = (const float*)d_in[12];
    const float* b5  = (const float*)d_in[13];
    const float* latent_norm = (const float*)d_in[14];

    float* ws      = (float*)d_ws;
    float* blkmax  = ws + OFF_BLKMAX;
    float* ae_part = ws + OFF_AEPART;
    float* lat     = ws + OFF_LAT;
    float* xd      = ws + OFF_XD;
    float* ld      = ws + OFF_LD;

    fused_mlp_pdistx_kernel<<<576, 256, 0, stream>>>(
        x, W1, b1, W2, b2, Wm, bm, W3, b3, W4, b4, W5, b5,
        lat, ae_part, xd, blkmax);
    mst_topk_kernel<<<128, 256, 0, stream>>>(
        xd, ld, lat, latent_norm, blkmax, ae_part, ws, (float*)d_out);
}

// Round 11
// 151.375 us; speedup vs baseline: 2.1110x; 2.1110x over previous
//
#include <hip/hip_runtime.h>
#include <math.h>

typedef unsigned long long ull;

#define N      512
#define DIN    256
#define LAM    0.43f
#define MAGIC  0x4D535431u
#define PAD(j) ((j) + (((j) >> 6) << 2))  // +4 words per 64 -> 2-way LDS banks

// ---------------------------------------------------------------------------
// ws word offsets (floats). Flags one-shot, compared ==MAGIC (0xAA/0 safe).
//   [4] ldready [5] t0ready [6] t0bits
//   [8..71] blkmax   [128..639] ae_part   +1024 lat[1024]
//   +2048 xd[262144]   +264192 ld[262144]
//   +526336 rowmin u64[2][2][512]  (m, phase parity; every phase rewrites all
//            512 slots before the barrier that precedes reads -> poison-safe)
//   +530432 bar u32[2][9][64]  (MAGIC one-shot barrier slots)
// end ~531584 floats ~2.13 MB
// ---------------------------------------------------------------------------
#define OFF_LDREADY 4
#define OFF_T0READY 5
#define OFF_T0BITS  6
#define OFF_BLKMAX  8
#define OFF_AEPART  128
#define OFF_LAT     1024
#define OFF_XD      2048
#define OFF_LD      (2048 + 262144)
#define OFF_ROWM    526336
#define OFF_BAR     (OFF_ROWM + 4096)

__device__ __forceinline__ unsigned ld_acq(unsigned* p) {
    return __hip_atomic_load(p, __ATOMIC_ACQUIRE, __HIP_MEMORY_SCOPE_AGENT);
}
__device__ __forceinline__ void st_rel(unsigned* p, unsigned v) {
    __hip_atomic_store(p, v, __ATOMIC_RELEASE, __HIP_MEMORY_SCOPE_AGENT);
}
__device__ __forceinline__ unsigned ld_rlx(unsigned* p) {
    return __hip_atomic_load(p, __ATOMIC_RELAXED, __HIP_MEMORY_SCOPE_AGENT);
}
__device__ __forceinline__ ull ld64_rlx(ull* p) {
    return __hip_atomic_load(p, __ATOMIC_RELAXED, __HIP_MEMORY_SCOPE_AGENT);
}
__device__ __forceinline__ void st64_rlx(ull* p, ull v) {
    __hip_atomic_store(p, v, __ATOMIC_RELAXED, __HIP_MEMORY_SCOPE_AGENT);
}
__device__ __forceinline__ void spin_magic(unsigned* p) {
    while (ld_acq(p) != MAGIC) __builtin_amdgcn_s_sleep(1);
}

// ============ kernel 1: fused MLP (blocks 0..511) + pdist_x (512..575) ======
// (unchanged from round 7 — proven)
__global__ __launch_bounds__(256) void fused_mlp_pdistx_kernel(
    const float* __restrict__ x,
    const float* __restrict__ W1, const float* __restrict__ b1,
    const float* __restrict__ W2, const float* __restrict__ b2,
    const float* __restrict__ Wm, const float* __restrict__ bm,
    const float* __restrict__ W3, const float* __restrict__ b3,
    const float* __restrict__ W4, const float* __restrict__ b4,
    const float* __restrict__ W5, const float* __restrict__ b5,
    float* __restrict__ lat_out, float* __restrict__ ae_part,
    float* __restrict__ xd, float* __restrict__ blkmax)
{
    const int tid = threadIdx.x;

    if (blockIdx.x < 512) {
        __shared__ float xs[256];
        __shared__ float h1[128];
        __shared__ float h2[64];
        __shared__ float latv[2];
        __shared__ float h3[64];
        __shared__ float h4[128];
        __shared__ float red[4];

        const int row = blockIdx.x;
        xs[tid] = x[(size_t)row * DIN + tid];
        __syncthreads();

        if (tid < 128) {
            float s = b1[tid];
            for (int k = 0; k < 256; ++k) s = fmaf(xs[k], W1[k * 128 + tid], s);
            h1[tid] = fmaxf(s, 0.f);
        }
        __syncthreads();

        if (tid < 64) {
            float s = b2[tid];
            for (int k = 0; k < 128; ++k) s = fmaf(h1[k], W2[k * 64 + tid], s);
            h2[tid] = fmaxf(s, 0.f);
        }
        __syncthreads();

        if (tid < 2) {
            float s = bm[tid];
            for (int k = 0; k < 64; ++k) s = fmaf(h2[k], Wm[k * 2 + tid], s);
            latv[tid] = s;
            lat_out[(size_t)row * 2 + tid] = s;
        }
        __syncthreads();

        if (tid < 64) {
            float s = b3[tid];
            s = fmaf(latv[0], W3[tid], s);
            s = fmaf(latv[1], W3[64 + tid], s);
            h3[tid] = fmaxf(s, 0.f);
        }
        __syncthreads();

        if (tid < 128) {
            float s = b4[tid];
            for (int k = 0; k < 64; ++k) s = fmaf(h3[k], W4[k * 128 + tid], s);
            h4[tid] = fmaxf(s, 0.f);
        }
        __syncthreads();

        float s = b5[tid];
        for (int k = 0; k < 128; ++k) s = fmaf(h4[k], W5[k * 256 + tid], s);
        float diff = xs[tid] - s;
        float a = diff * diff;

        #pragma unroll
        for (int m = 1; m < 64; m <<= 1) a += __shfl_xor(a, m, 64);
        if ((tid & 63) == 0) red[tid >> 6] = a;
        __syncthreads();
        if (tid == 0) ae_part[row] = red[0] + red[1] + red[2] + red[3];
    } else {
        __shared__ float As[32][65];
        __shared__ float Bs[32][65];
        __shared__ float red2[4];

        const int bid = blockIdx.x - 512;
        const int bi = bid & 7, bj = bid >> 3;
        const int i0 = bi * 64, j0 = bj * 64;
        const int ty = tid >> 4, tx = tid & 15;

        float acc[4][4];
        #pragma unroll
        for (int i = 0; i < 4; ++i)
            #pragma unroll
            for (int j = 0; j < 4; ++j) acc[i][j] = 0.f;

        for (int kk = 0; kk < DIN; kk += 32) {
            #pragma unroll
            for (int s = tid; s < 512; s += 256) {
                int r = s >> 3, c4 = (s & 7) << 2;
                float4 va = *(const float4*)(x + (size_t)(i0 + r) * DIN + kk + c4);
                As[c4 + 0][r] = va.x; As[c4 + 1][r] = va.y;
                As[c4 + 2][r] = va.z; As[c4 + 3][r] = va.w;
                float4 vb = *(const float4*)(x + (size_t)(j0 + r) * DIN + kk + c4);
                Bs[c4 + 0][r] = vb.x; Bs[c4 + 1][r] = vb.y;
                Bs[c4 + 2][r] = vb.z; Bs[c4 + 3][r] = vb.w;
            }
            __syncthreads();
            #pragma unroll 8
            for (int k = 0; k < 32; ++k) {
                float a[4], b[4];
                #pragma unroll
                for (int i = 0; i < 4; ++i) a[i] = As[k][ty + 16 * i];
                #pragma unroll
                for (int j = 0; j < 4; ++j) b[j] = Bs[k][tx + 16 * j];
                #pragma unroll
                for (int i = 0; i < 4; ++i)
                    #pragma unroll
                    for (int j = 0; j < 4; ++j) {
                        float d = a[i] - b[j];
                        acc[i][j] = fmaf(d, d, acc[i][j]);
                    }
            }
            __syncthreads();
        }

        float lmax = 0.f;
        #pragma unroll
        for (int i = 0; i < 4; ++i)
            #pragma unroll
            for (int j = 0; j < 4; ++j) {
                float dd = sqrtf(acc[i][j]);
                int r = i0 + ty + 16 * i, c = j0 + tx + 16 * j;
                xd[(size_t)r * N + c] = dd;
                lmax = fmaxf(lmax, dd);
            }

        #pragma unroll
        for (int m = 32; m >= 1; m >>= 1) lmax = fmaxf(lmax, __shfl_xor(lmax, m, 64));
        if ((tid & 63) == 0) red2[tid >> 6] = lmax;
        __syncthreads();
        if (tid == 0)
            blkmax[bid] = fmaxf(fmaxf(red2[0], red2[1]), fmaxf(red2[2], red2[3]));
    }
}

// ============ kernel 2: register-resident distributed Boruvka x2 ============
// 128 blocks x 256. Blocks 0..63 -> MST(xd), 64..127 -> MST(ld).
// Thread layout: row r = wb*8 + (tid>>5); cols c0 = (tid&31)*16 .. +15.
// The 16 weights live in REGISTERS (loaded/computed once). Per phase:
//   scan: 16 LDS comp lookups + u64 key select; 5-step shfl group-reduce;
//   owner-exclusive relaxed store of per-row min to rowmin[parity][r];
//   global MAGIC barrier; each block gathers 512 row-mins, LDS per-comp
//   read-check+atomicMin, redundant hook + ADAPTIVE pointer doubling.
// Key = w<<18 | r<<9 | j (unique MST = Kruskal's edge set).
__global__ __launch_bounds__(256) void mst_regs_kernel(
    const float* __restrict__ xd, float* __restrict__ ld,
    const float* __restrict__ lat, const float* __restrict__ latent_norm,
    const float* __restrict__ blkmax, const float* __restrict__ ae_part,
    float* __restrict__ wsf, float* __restrict__ out)
{
    __shared__ unsigned comp_a[512];
    __shared__ __align__(16) unsigned comp_s[544];
    __shared__ ull cnd[512];
    __shared__ int tgt[512];
    __shared__ unsigned short eu[512], ev[512];
    __shared__ float ew[512];
    __shared__ float latx[512], laty[512];
    __shared__ float s_red[4];
    __shared__ float s_xdm;
    __shared__ int s_ecnt, s_chg;

    const int tid = threadIdx.x;
    const int blk = blockIdx.x;
    const int m   = blk >> 6;
    const int wb  = blk & 63;
    const bool leader = (wb == 0);
    const int r  = (wb << 3) + (tid >> 5);   // owned row
    const int c0 = (tid & 31) << 4;          // first owned col

    unsigned* ldready = (unsigned*)(wsf + OFF_LDREADY);
    unsigned* t0ready = (unsigned*)(wsf + OFF_T0READY);
    unsigned* t0bits  = (unsigned*)(wsf + OFF_T0BITS);
    ull* rowm = (ull*)(wsf + OFF_ROWM) + (size_t)m * 1024;   // 2 parities x 512
    unsigned* bar = (unsigned*)(wsf + OFF_BAR) + (size_t)m * 576;  // 9 x 64

    const float* Om = m ? xd : ld;

    unsigned wbits[16];

    // ---- load/compute the owned 16 weights into registers ----
    if (m == 1) {
        for (int i = tid; i < 512; i += 256) {
            float2 v = *(const float2*)(lat + 2 * i);
            latx[i] = v.x; laty[i] = v.y;
        }
        __syncthreads();
        const float xi = latx[r], yi = laty[r];
        float dv[16];
        #pragma unroll
        for (int s = 0; s < 16; ++s) {
            float dx = xi - latx[c0 + s], dy = yi - laty[c0 + s];
            dv[s] = sqrtf(fmaf(dx, dx, dy * dy));
            wbits[s] = __float_as_uint(dv[s]);
        }
        #pragma unroll
        for (int q = 0; q < 4; ++q) {
            float4 o = make_float4(dv[4 * q], dv[4 * q + 1], dv[4 * q + 2], dv[4 * q + 3]);
            *(float4*)(ld + (size_t)r * N + c0 + 4 * q) = o;
        }
    } else {
        #pragma unroll
        for (int q = 0; q < 4; ++q) {
            float4 f = *(const float4*)(xd + (size_t)r * N + c0 + 4 * q);
            wbits[4 * q + 0] = __float_as_uint(f.x);
            wbits[4 * q + 1] = __float_as_uint(f.y);
            wbits[4 * q + 2] = __float_as_uint(f.z);
            wbits[4 * q + 3] = __float_as_uint(f.w);
        }
    }

    // ---- init union-find state ----
    for (int i = tid; i < 512; i += 256) {
        comp_a[i] = (unsigned)i;
        comp_s[PAD(i)] = (unsigned)i;
    }
    if (tid == 0) s_ecnt = 0;
    __syncthreads();

    // ---- Boruvka phases (components at least halve -> <=9) ----
    int nc = 512;
    for (int p = 0; p < 9 && nc > 1; ++p) {
        // reset per-comp candidates (used after the barrier)
        for (int i = tid; i < 512; i += 256) cnd[i] = ~0ULL;

        // --- scan from registers: min cross-comp key of this thread's 16 ---
        const unsigned cv = comp_s[PAD(r)];
        ull bk = ~0ULL;
        #pragma unroll
        for (int s = 0; s < 16; ++s) {
            int j = c0 + s;
            unsigned cj = comp_s[PAD(j)];
            ull k = ((ull)wbits[s] << 18) | ((ull)r << 9) | (unsigned)j;
            if (cj != cv && k < bk) bk = k;
        }
        #pragma unroll
        for (int mm = 1; mm <= 16; mm <<= 1) {     // reduce within 32-lane row group
            ull o = __shfl_xor(bk, mm, 64);
            if (o < bk) bk = o;
        }
        if ((tid & 31) == 0) st64_rlx(&rowm[(size_t)(p & 1) * 512 + r], bk);

        // --- one all-to-all barrier per phase ---
        __syncthreads();
        if (tid == 0) st_rel(&bar[p * 64 + wb], MAGIC);
        if (tid < 64) spin_magic(&bar[p * 64 + tid]);
        __syncthreads();
        if (p == 0 && m == 1 && leader && tid == 0)
            st_rel(ldready, MAGIC);                // all ld stores now HB-visible

        // --- gather row-mins, per-comp min into LDS (read-check first) ---
        for (int i = tid; i < 512; i += 256) {
            ull kk = ld64_rlx(&rowm[(size_t)(p & 1) * 512 + i]);
            if (kk != ~0ULL) {
                unsigned c = comp_a[i];
                if (kk < cnd[c]) atomicMin(&cnd[c], kk);
            }
        }
        __syncthreads();

        // --- hook (mutual pairs broken by index) + record edges ---
        for (int i = tid; i < 512; i += 256) {
            int t = -1;
            if (comp_a[i] == (unsigned)i && cnd[i] != ~0ULL)
                t = (int)comp_a[cnd[i] & 511];
            tgt[i] = t;
        }
        __syncthreads();
        for (int i = tid; i < 512; i += 256) {
            int s2 = tgt[i];
            if (s2 >= 0 && !(tgt[s2] == i && i > s2)) {
                comp_a[i] = (unsigned)s2;
                int e = atomicAdd(&s_ecnt, 1);
                ull cc = cnd[i];
                eu[e] = (unsigned short)((cc >> 9) & 511);
                ev[e] = (unsigned short)(cc & 511);
                ew[e] = __uint_as_float((unsigned)(cc >> 18));
            }
        }
        __syncthreads();

        // --- adaptive pointer doubling (typ. 3 rounds; exact, max 9) ---
        for (int dd = 0; dd < 9; ++dd) {
            if (tid == 0) s_chg = 0;
            __syncthreads();
            unsigned a = comp_a[comp_a[tid]];
            unsigned b = comp_a[comp_a[tid + 256]];
            if (a != comp_a[tid] || b != comp_a[tid + 256]) s_chg = 1;
            __syncthreads();
            comp_a[tid] = a; comp_a[tid + 256] = b;
            __syncthreads();
            if (!s_chg) break;
        }
        for (int i = tid; i < 512; i += 256) comp_s[PAD(i)] = comp_a[i];
        nc = 512 - s_ecnt;
        __syncthreads();
    }

    // =================== epilogue (leaders only) ===================
    if (!leader) return;

    if (tid < 64) {
        float mx = blkmax[tid];
        #pragma unroll
        for (int mm = 32; mm >= 1; mm >>= 1) mx = fmaxf(mx, __shfl_xor(mx, mm, 64));
        if (tid == 0) s_xdm = mx;
    }
    __syncthreads();
    const float xdm = s_xdm;
    const float lnv = latent_norm[0];
    const float sD = (m == 0) ? 1.f / xdm : 1.f / lnv;
    const float sO = (m == 0) ? 1.f / lnv : 1.f / xdm;

    if (m == 0) {                          // need full ld for Om reads
        if (tid == 0) spin_magic(ldready);
        __syncthreads();
    }

    const int ne = s_ecnt;                 // 511
    float acc = 0.f;
    for (int i = tid; i < ne; i += 256) {
        float de = ew[i];
        float oe = Om[(size_t)eu[i] * N + ev[i]];
        float c = sD * de - sO * oe;
        acc = fmaf(c, c, acc);
    }
    #pragma unroll
    for (int mm = 32; mm >= 1; mm >>= 1) acc += __shfl_xor(acc, mm, 64);
    if ((tid & 63) == 0) s_red[tid >> 6] = acc;
    __syncthreads();

    if (m == 0) {
        if (tid == 0) {
            float t0 = s_red[0] + s_red[1] + s_red[2] + s_red[3];
            __hip_atomic_store(t0bits, __float_as_uint(t0), __ATOMIC_RELAXED,
                               __HIP_MEMORY_SCOPE_AGENT);
            st_rel(t0ready, MAGIC);
        }
    } else {
        float t1 = 0.f;
        if (tid == 0) t1 = s_red[0] + s_red[1] + s_red[2] + s_red[3];
        __syncthreads();                   // s_red reused
        float a = ae_part[tid] + ae_part[tid + 256];
        #pragma unroll
        for (int mm = 32; mm >= 1; mm >>= 1) a += __shfl_xor(a, mm, 64);
        if ((tid & 63) == 0) s_red[tid >> 6] = a;
        __syncthreads();
        if (tid == 0) {
            float ae = s_red[0] + s_red[1] + s_red[2] + s_red[3];
            spin_magic(t0ready);
            float t0 = __uint_as_float(ld_rlx(t0bits));
            out[0] = ae * (1.f / (float)(N * DIN))
                   + (LAM * (t0 + t1)) * (1.f / (float)N);
        }
    }
}

extern "C" void kernel_launch(void* const* d_in, const int* in_sizes, int n_in,
                              void* d_out, int out_size, void* d_ws, size_t ws_size,
                              hipStream_t stream) {
    (void)in_sizes; (void)n_in; (void)out_size; (void)ws_size;
    const float* x   = (const float*)d_in[0];
    // d_in[1] = label (unused)
    const float* W1  = (const float*)d_in[2];
    const float* b1  = (const float*)d_in[3];
    const float* W2  = (const float*)d_in[4];
    const float* b2  = (const float*)d_in[5];
    const float* Wm  = (const float*)d_in[6];
    const float* bm  = (const float*)d_in[7];
    const float* W3  = (const float*)d_in[8];
    const float* b3  = (const float*)d_in[9];
    const float* W4  = (const float*)d_in[10];
    const float* b4  = (const float*)d_in[11];
    const float* W5  = (const float*)d_in[12];
    const float* b5  = (const float*)d_in[13];
    const float* latent_norm = (const float*)d_in[14];

    float* ws      = (float*)d_ws;
    float* blkmax  = ws + OFF_BLKMAX;
    float* ae_part = ws + OFF_AEPART;
    float* lat     = ws + OFF_LAT;
    float* xd      = ws + OFF_XD;
    float* ld      = ws + OFF_LD;

    fused_mlp_pdistx_kernel<<<576, 256, 0, stream>>>(
        x, W1, b1, W2, b2, Wm, bm, W3, b3, W4, b4, W5, b5,
        lat, ae_part, xd, blkmax);
    mst_regs_kernel<<<128, 256, 0, stream>>>(
        xd, ld, lat, latent_norm, blkmax, ae_part, ws, (float*)d_out);
}